// Round 13
// baseline (585.673 us; speedup 1.0000x reference)
//
#include <hip/hip_runtime.h>
#include <stdint.h>

#define TL  2048
#define NB  4096
#define INSZ 8
#define HID 10
#define LOG2E 1.4426950408889634f
#define XS (NB * INSZ)            // floats per timestep slab
#define TSTEPS 8                  // timesteps per staged tile (1 KB DMA)
#define NBUF 4
#define NTILES (TL / TSTEPS)      // 256
#define WSLOT 80                  // padded per-j weight slot (76 used)

__device__ __forceinline__ float rcp_(float x)  { return __builtin_amdgcn_rcpf(x); }
__device__ __forceinline__ float exp2_(float x) { return __builtin_amdgcn_exp2f(x); }

// row_newbcast:K (DPP ctrl 0x150+K): every lane of each 16-lane row receives
// src from lane K of that row. old=0 + bound_ctrl=true + full masks -> old is
// provably unread -> folds to a SINGLE v_mov_b32_dpp (no tied-copy pair).
template<int K> __device__ __forceinline__ float bcast16(float x) {
    return __int_as_float(__builtin_amdgcn_update_dpp(
        0, __float_as_int(x), 0x150 + K, 0xF, 0xF, true));
}

// One LSTM step, pure C. Weights pre-scaled by -log2e (i,f,o) / -2log2e (g)
// so every sigmoid/tanh is exp2-based; ONE batched rcp serves all 4 gates.
__device__ __forceinline__ void lstm_step(const float4& X0, const float4& X1,
        const float (&wx)[4][INSZ], const float (&wh)[4][HID], const float (&bs)[4],
        float& hst, float& cst) {
    float a0 = bs[0], a1 = bs[1], a2 = bs[2], a3 = bs[3];
    const float xv[INSZ] = {X0.x, X0.y, X0.z, X0.w, X1.x, X1.y, X1.z, X1.w};
#pragma unroll
    for (int i = 0; i < INSZ; ++i) {
        a0 = fmaf(wx[0][i], xv[i], a0);
        a1 = fmaf(wx[1][i], xv[i], a1);
        a2 = fmaf(wx[2][i], xv[i], a2);
        a3 = fmaf(wx[3][i], xv[i], a3);
    }
#define HTERM(K) do { \
        const float hk = bcast16<K>(hst); \
        a0 = fmaf(wh[0][K], hk, a0); \
        a1 = fmaf(wh[1][K], hk, a1); \
        a2 = fmaf(wh[2][K], hk, a2); \
        a3 = fmaf(wh[3][K], hk, a3); \
    } while (0)
    HTERM(0); HTERM(1); HTERM(2); HTERM(3); HTERM(4);
    HTERM(5); HTERM(6); HTERM(7); HTERM(8); HTERM(9);
#undef HTERM
    // Batched reciprocal: r = 1/(d0 d1 d2 d3); overflow-safe (each d <= ~2^25).
    const float d0 = 1.f + exp2_(a0);
    const float d1 = 1.f + exp2_(a1);
    const float d2 = 1.f + exp2_(a2);
    const float d3 = 1.f + exp2_(a3);
    const float p01 = d0 * d1, p23 = d2 * d3;
    const float r   = rcp_(p01 * p23);
    const float r01 = r * p23, r23 = r * p01;
    const float ig = r01 * d1;                    // 1/d0 = sigmoid(i)
    const float fg = r01 * d0;                    // 1/d1 = sigmoid(f)
    const float gg = fmaf(2.f, r23 * d3, -1.f);   // 2/d2-1 = tanh(g)
    const float og = r23 * d2;                    // 1/d3 = sigmoid(o)
    cst = fmaf(fg, cst, ig * gg);
    const float th = fmaf(2.f, rcp_(1.f + exp2_(cst * (-2.f * LOG2E))), -1.f);
    hst = og * th;
}

// One global_load_lds dwordx4: lane l's 16 B -> ldsbase + l*16 (wave-uniform
// base, linear lane layout). Consumers read through LDS (memory), so the
// "memory"-clobbered counted waits order them correctly (R7-proven).
__device__ __forceinline__ void stage_tile(const float* gsrc_lane, float* ldsbase) {
    __builtin_amdgcn_global_load_lds(
        (const __attribute__((address_space(1))) void*)(uintptr_t)gsrc_lane,
        (__attribute__((address_space(3))) void*)(uint32_t)(uintptr_t)ldsbase,
        16, 0, 0);
}

template<int VM>
__device__ __forceinline__ void consume_tile(const float (&xb)[TSTEPS][4][INSZ],
        int grp, const float (&wx)[4][INSZ], const float (&wh)[4][HID],
        const float (&bs)[4], float& hst, float& cst) {
    asm volatile("s_waitcnt vmcnt(%0)" :: "i"(VM) : "memory");
#pragma unroll
    for (int s = 0; s < TSTEPS; ++s) {
        const float4 xlo = *(const float4*)&xb[s][grp][0];
        const float4 xhi = *(const float4*)&xb[s][grp][4];
        lstm_step(xlo, xhi, wx, wh, bs, hst, cst);
    }
}

// 16 lanes per chain, 4 chains per wave, 1024 waves = 1 wave/SIMD.
// Lane j16<10 owns hidden unit j: gate rows {j,10+j,20+j,30+j}.
// h exchanged via DPP row_newbcast. x staged via 4-deep LDS DMA pipeline.
// Weights are made OPAQUE via an LDS round-trip: ds_read of another lane's
// store is neither invariant nor rematerializable -> must stay in VGPRs
// (R7/R11/R12's VGPR=64-72 proved invariant global loads get rematerialized).
__global__ void __attribute__((amdgpu_flat_work_group_size(64, 64)))
                __attribute__((amdgpu_waves_per_eu(1)))
lstm_fused(
    const float* __restrict__ x,
    const float* __restrict__ h0,
    const float* __restrict__ c0,
    const float* __restrict__ Wih,
    const float* __restrict__ Whh,
    const float* __restrict__ bih,
    const float* __restrict__ bhh,
    const float* __restrict__ Wfc,
    const float* __restrict__ bfc,
    float* __restrict__ out)
{
    __shared__ float xbuf[NBUF][TSTEPS][4][INSZ];   // 4 KB
    __shared__ float wlds[16][WSLOT];               // 5 KB scaled-weight slots

    const int lane = threadIdx.x;
    const int j16  = lane & 15;
    const int grp  = lane >> 4;
    const int n    = ((int)blockIdx.x << 2) + grp;
    const int j    = (j16 < HID) ? j16 : 0;   // clamp padding lanes
    const int src  = lane & 48;               // 16-lane group base

    // grp-0 lanes produce the scaled weight set for their j16 slot.
    if (grp == 0) {
#pragma unroll
        for (int g = 0; g < 4; ++g) {
            const int row = g * HID + j;
            const float s = (g == 2 ? -2.f : -1.f) * LOG2E;
#pragma unroll
            for (int i = 0; i < INSZ; ++i)
                wlds[j16][g * INSZ + i] = Wih[row * INSZ + i] * s;
#pragma unroll
            for (int k = 0; k < HID; ++k)
                wlds[j16][32 + g * HID + k] = Whh[row * HID + k] * s;
            wlds[j16][72 + g] = (bih[row] + bhh[row]) * s;
        }
    }
    __syncthreads();

    // Every lane reads its 76 weights back: opaque, register-resident.
    float wx[4][INSZ], wh[4][HID], bs[4];
#pragma unroll
    for (int g = 0; g < 4; ++g) {
#pragma unroll
        for (int i = 0; i < INSZ; ++i) wx[g][i] = wlds[j16][g * INSZ + i];
#pragma unroll
        for (int k = 0; k < HID; ++k) wh[g][k] = wlds[j16][32 + g * HID + k];
        bs[g] = wlds[j16][72 + g];
    }

    float cst = c0[n * HID + j];
    float hst = h0[n * HID + j];

    // Per-lane staging source: lane l covers (ts = l>>3, chain = (l>>1)&3,
    // half = l&1) -> LDS byte l*16 matches xbuf[..][ts][chain][half*4..+3].
    const int ts = lane >> 3, ch = (lane >> 1) & 3, hf = lane & 1;
    const float* gl = x + (size_t)ts * XS
                        + (size_t)((((int)blockIdx.x << 2) + ch) * INSZ + hf * 4);

    asm volatile("" ::: "memory");
#pragma unroll
    for (int b = 0; b < NBUF; ++b) {
        stage_tile(gl, &xbuf[b][0][0][0]);
        asm volatile("" ::: "memory");
        gl += (size_t)TSTEPS * XS;
    }

    // Main: counted vmcnt(3) completes exactly the oldest (this tile's) DMA;
    // lgkmcnt(0) ensures the buffer's ds_reads retired before its rewrite.
    for (int tile = 0; tile < NTILES - NBUF; ++tile) {
        const int b = tile & (NBUF - 1);
        consume_tile<3>(xbuf[b], grp, wx, wh, bs, hst, cst);
        asm volatile("s_waitcnt lgkmcnt(0)" ::: "memory");
        stage_tile(gl, &xbuf[b][0][0][0]);
        asm volatile("" ::: "memory");
        gl += (size_t)TSTEPS * XS;
    }
    // Drain: descending counted waits, no reissue.
    consume_tile<3>(xbuf[0], grp, wx, wh, bs, hst, cst);
    consume_tile<2>(xbuf[1], grp, wx, wh, bs, hst, cst);
    consume_tile<1>(xbuf[2], grp, wx, wh, bs, hst, cst);
    consume_tile<0>(xbuf[3], grp, wx, wh, bs, hst, cst);

    // epilogue (one-time, DS shuffles fine here): y = h @ W_fc.T + b_fc; dump h, c
    float hv[HID];
#pragma unroll
    for (int k = 0; k < HID; ++k) hv[k] = __shfl(hst, src + k, 64);

    if (j16 < INSZ) {
        float acc = bfc[j16];
#pragma unroll
        for (int k = 0; k < HID; ++k) acc = fmaf(Wfc[j16 * HID + k], hv[k], acc);
        out[n * INSZ + j16] = acc;
    }
    if (j16 < HID) {
        out[NB * INSZ + n * HID + j16] = hst;
        out[NB * INSZ + NB * HID + n * HID + j16] = cst;
    }
}

extern "C" void kernel_launch(void* const* d_in, const int* in_sizes, int n_in,
                              void* d_out, int out_size, void* d_ws, size_t ws_size,
                              hipStream_t stream) {
    const float* x   = (const float*)d_in[0];
    const float* h0  = (const float*)d_in[1];
    const float* c0  = (const float*)d_in[2];
    const float* Wih = (const float*)d_in[3];
    const float* Whh = (const float*)d_in[4];
    const float* bih = (const float*)d_in[5];
    const float* bhh = (const float*)d_in[6];
    const float* Wfc = (const float*)d_in[7];
    const float* bfc = (const float*)d_in[8];
    float* out = (float*)d_out;

    lstm_fused<<<NB / 4, 64, 0, stream>>>(x, h0, c0, Wih, Whh, bih, bhh, Wfc, bfc, out);
}

// Round 14
// 449.291 us; speedup vs baseline: 1.3035x; 1.3035x over previous
//
#include <hip/hip_runtime.h>
#include <stdint.h>

#define TL  2048
#define NB  4096
#define INSZ 8
#define HID 10
#define LOG2E 1.4426950408889634f
#define XS (NB * INSZ)            // floats per timestep slab
#define TSTEPS 8                  // timesteps per staged tile (1 KB DMA)
#define NBUF 4
#define NTILES (TL / TSTEPS)      // 256

__device__ __forceinline__ float rcp_(float x)  { return __builtin_amdgcn_rcpf(x); }
__device__ __forceinline__ float exp2_(float x) { return __builtin_amdgcn_exp2f(x); }

// row_newbcast:K (DPP ctrl 0x150+K): every lane of each 16-lane row receives
// src from lane K of that row. old=0 + bound_ctrl=true + full masks -> old is
// provably unread -> folds to a SINGLE v_mov_b32_dpp.
template<int K> __device__ __forceinline__ float bcast16(float x) {
    return __int_as_float(__builtin_amdgcn_update_dpp(
        0, __float_as_int(x), 0x150 + K, 0xF, 0xF, true));
}

// One LSTM step, pure C. Weights pre-scaled by -log2e (i,f,o) / -2log2e (g)
// so every sigmoid/tanh is exp2-based; ONE batched rcp serves all 4 gates.
__device__ __forceinline__ void lstm_step(const float4& X0, const float4& X1,
        const float (&wx)[4][INSZ], const float (&wh)[4][HID], const float (&bs)[4],
        float& hst, float& cst) {
    float a0 = bs[0], a1 = bs[1], a2 = bs[2], a3 = bs[3];
    const float xv[INSZ] = {X0.x, X0.y, X0.z, X0.w, X1.x, X1.y, X1.z, X1.w};
#pragma unroll
    for (int i = 0; i < INSZ; ++i) {
        a0 = fmaf(wx[0][i], xv[i], a0);
        a1 = fmaf(wx[1][i], xv[i], a1);
        a2 = fmaf(wx[2][i], xv[i], a2);
        a3 = fmaf(wx[3][i], xv[i], a3);
    }
#define HTERM(K) do { \
        const float hk = bcast16<K>(hst); \
        a0 = fmaf(wh[0][K], hk, a0); \
        a1 = fmaf(wh[1][K], hk, a1); \
        a2 = fmaf(wh[2][K], hk, a2); \
        a3 = fmaf(wh[3][K], hk, a3); \
    } while (0)
    HTERM(0); HTERM(1); HTERM(2); HTERM(3); HTERM(4);
    HTERM(5); HTERM(6); HTERM(7); HTERM(8); HTERM(9);
#undef HTERM
    // Batched reciprocal: r = 1/(d0 d1 d2 d3); overflow-safe (each d <= ~2^25).
    const float d0 = 1.f + exp2_(a0);
    const float d1 = 1.f + exp2_(a1);
    const float d2 = 1.f + exp2_(a2);
    const float d3 = 1.f + exp2_(a3);
    const float p01 = d0 * d1, p23 = d2 * d3;
    const float r   = rcp_(p01 * p23);
    const float r01 = r * p23, r23 = r * p01;
    const float ig = r01 * d1;                    // 1/d0 = sigmoid(i)
    const float fg = r01 * d0;                    // 1/d1 = sigmoid(f)
    const float gg = fmaf(2.f, r23 * d3, -1.f);   // 2/d2-1 = tanh(g)
    const float og = r23 * d2;                    // 1/d3 = sigmoid(o)
    cst = fmaf(fg, cst, ig * gg);
    const float th = fmaf(2.f, rcp_(1.f + exp2_(cst * (-2.f * LOG2E))), -1.f);
    hst = og * th;
}

// One global_load_lds dwordx4: lane l's 16 B -> ldsbase + l*16 (wave-uniform
// base, linear lane layout). Consumers read through LDS (memory), so the
// "memory"-clobbered counted waits order them correctly (R7-proven).
__device__ __forceinline__ void stage_tile(const float* gsrc_lane, float* ldsbase) {
    __builtin_amdgcn_global_load_lds(
        (const __attribute__((address_space(1))) void*)(uintptr_t)gsrc_lane,
        (__attribute__((address_space(3))) void*)(uint32_t)(uintptr_t)ldsbase,
        16, 0, 0);
}

template<int VM>
__device__ __forceinline__ void consume_tile(const float (&xb)[TSTEPS][4][INSZ],
        int grp, const float (&wx)[4][INSZ], const float (&wh)[4][HID],
        const float (&bs)[4], float& hst, float& cst) {
    asm volatile("s_waitcnt vmcnt(%0)" :: "i"(VM) : "memory");
    // Read the whole tile into registers first (one batch of ds_read latency
    // per tile; with waves_per_eu(1,1) the registers are free).
    float4 xlo[TSTEPS], xhi[TSTEPS];
#pragma unroll
    for (int s = 0; s < TSTEPS; ++s) {
        xlo[s] = *(const float4*)&xb[s][grp][0];
        xhi[s] = *(const float4*)&xb[s][grp][4];
    }
#pragma unroll
    for (int s = 0; s < TSTEPS; ++s)
        lstm_step(xlo[s], xhi[s], wx, wh, bs, hst, cst);
}

// 16 lanes per chain, 4 chains per wave, 1024 waves = 1 wave/SIMD.
// Lane j16<10 owns hidden unit j: gate rows {j,10+j,20+j,30+j}.
// h exchanged via DPP row_newbcast. x staged via 4-deep LDS DMA pipeline.
//
// waves_per_eu(1,1): max=1 disarms the scheduler's occupancy-driven register
// squeeze (R7-R13: targeting 8 waves/EU it remat'd/spilled the 76-float
// weight set every step -> ~150 extra issue-cy/step). With target=1 the
// allocator has a 512-VGPR budget and no incentive to shrink.
__global__ void __attribute__((amdgpu_flat_work_group_size(64, 64)))
                __attribute__((amdgpu_waves_per_eu(1, 1)))
lstm_fused(
    const float* __restrict__ x,
    const float* __restrict__ h0,
    const float* __restrict__ c0,
    const float* __restrict__ Wih,
    const float* __restrict__ Whh,
    const float* __restrict__ bih,
    const float* __restrict__ bhh,
    const float* __restrict__ Wfc,
    const float* __restrict__ bfc,
    float* __restrict__ out)
{
    __shared__ float xbuf[NBUF][TSTEPS][4][INSZ];   // 4 KB

    const int lane = threadIdx.x;
    const int j16  = lane & 15;
    const int grp  = lane >> 4;
    const int n    = ((int)blockIdx.x << 2) + grp;
    const int j    = (j16 < HID) ? j16 : 0;   // clamp padding lanes
    const int src  = lane & 48;               // 16-lane group base

    // Weights in plain float arrays (76 regs), activation scale folded in.
    float wx[4][INSZ], wh[4][HID], bs[4];
#pragma unroll
    for (int g = 0; g < 4; ++g) {
        const int row = g * HID + j;
        const float s = (g == 2 ? -2.f : -1.f) * LOG2E;
#pragma unroll
        for (int i = 0; i < INSZ; ++i) wx[g][i] = Wih[row * INSZ + i] * s;
#pragma unroll
        for (int k = 0; k < HID; ++k) wh[g][k] = Whh[row * HID + k] * s;
        bs[g] = (bih[row] + bhh[row]) * s;
    }

    float cst = c0[n * HID + j];
    float hst = h0[n * HID + j];

    // Per-lane staging source: lane l covers (ts = l>>3, chain = (l>>1)&3,
    // half = l&1) -> LDS byte l*16 matches xbuf[..][ts][chain][half*4..+3].
    const int ts = lane >> 3, ch = (lane >> 1) & 3, hf = lane & 1;
    const float* gl = x + (size_t)ts * XS
                        + (size_t)((((int)blockIdx.x << 2) + ch) * INSZ + hf * 4);

    asm volatile("" ::: "memory");
#pragma unroll
    for (int b = 0; b < NBUF; ++b) {
        stage_tile(gl, &xbuf[b][0][0][0]);
        asm volatile("" ::: "memory");
        gl += (size_t)TSTEPS * XS;
    }

    // Main: counted vmcnt(3) completes exactly the oldest (this tile's) DMA;
    // lgkmcnt(0) ensures the buffer's ds_reads retired before its rewrite.
    for (int tile = 0; tile < NTILES - NBUF; ++tile) {
        const int b = tile & (NBUF - 1);
        consume_tile<3>(xbuf[b], grp, wx, wh, bs, hst, cst);
        asm volatile("s_waitcnt lgkmcnt(0)" ::: "memory");
        stage_tile(gl, &xbuf[b][0][0][0]);
        asm volatile("" ::: "memory");
        gl += (size_t)TSTEPS * XS;
    }
    // Drain: descending counted waits, no reissue.
    consume_tile<3>(xbuf[0], grp, wx, wh, bs, hst, cst);
    consume_tile<2>(xbuf[1], grp, wx, wh, bs, hst, cst);
    consume_tile<1>(xbuf[2], grp, wx, wh, bs, hst, cst);
    consume_tile<0>(xbuf[3], grp, wx, wh, bs, hst, cst);

    // epilogue (one-time, DS shuffles fine here): y = h @ W_fc.T + b_fc; dump h, c
    float hv[HID];
#pragma unroll
    for (int k = 0; k < HID; ++k) hv[k] = __shfl(hst, src + k, 64);

    if (j16 < INSZ) {
        float acc = bfc[j16];
#pragma unroll
        for (int k = 0; k < HID; ++k) acc = fmaf(Wfc[j16 * HID + k], hv[k], acc);
        out[n * INSZ + j16] = acc;
    }
    if (j16 < HID) {
        out[NB * INSZ + n * HID + j16] = hst;
        out[NB * INSZ + NB * HID + n * HID + j16] = cst;
    }
}

extern "C" void kernel_launch(void* const* d_in, const int* in_sizes, int n_in,
                              void* d_out, int out_size, void* d_ws, size_t ws_size,
                              hipStream_t stream) {
    const float* x   = (const float*)d_in[0];
    const float* h0  = (const float*)d_in[1];
    const float* c0  = (const float*)d_in[2];
    const float* Wih = (const float*)d_in[3];
    const float* Whh = (const float*)d_in[4];
    const float* bih = (const float*)d_in[5];
    const float* bhh = (const float*)d_in[6];
    const float* Wfc = (const float*)d_in[7];
    const float* bfc = (const float*)d_in[8];
    float* out = (float*)d_out;

    lstm_fused<<<NB / 4, 64, 0, stream>>>(x, h0, c0, Wih, Whh, bih, bhh, Wfc, bfc, out);
}

// Round 15
// 355.599 us; speedup vs baseline: 1.6470x; 1.2635x over previous
//
#include <hip/hip_runtime.h>
#include <stdint.h>

#define TL  2048
#define NB  4096
#define INSZ 8
#define HID 10
#define LOG2E 1.4426950408889634f
#define XS (NB * INSZ)            // floats per timestep slab
#define TSTEPS 8                  // timesteps per staged tile (1 KB DMA)
#define NBUF 4
#define NTILES (TL / TSTEPS)      // 256

typedef float v2f __attribute__((ext_vector_type(2)));

__device__ __forceinline__ float rcp_(float x)  { return __builtin_amdgcn_rcpf(x); }
__device__ __forceinline__ float exp2_(float x) { return __builtin_amdgcn_exp2f(x); }

// row_newbcast:K (DPP ctrl 0x150+K): every lane of each 16-lane row receives
// src from lane K of that row. old=0 + bound_ctrl=true + full masks -> old is
// provably unread -> folds to a SINGLE v_mov_b32_dpp.
template<int K> __device__ __forceinline__ float bcast16(float x) {
    return __int_as_float(__builtin_amdgcn_update_dpp(
        0, __float_as_int(x), 0x150 + K, 0xF, 0xF, true));
}

// One LSTM step. Gate pairs (i,f)->01 and (g,o)->23 ride in float2 halves;
// __builtin_elementwise_fma on <2 x float> lowers to v_pk_fma_f32 (2 FMAs at
// one 2-cy wave issue) with splat operands folded via op_sel. Pure C body —
// no inline asm in the loop (R7/R11: asm bodies degrade LLVM scheduling).
// Weights pre-scaled by -log2e (i,f,o) / -2log2e (g); ONE batched rcp serves
// all 4 gate activations.
__device__ __forceinline__ void lstm_step(const float4& X0, const float4& X1,
        const v2f (&wx01)[INSZ], const v2f (&wx23)[INSZ],
        const v2f (&wh01)[HID], const v2f (&wh23)[HID],
        const v2f& b01, const v2f& b23, float& hst, float& cst) {
    v2f a01e = b01, a23e = b23;
    v2f a01o = {0.f, 0.f}, a23o = {0.f, 0.f};
    const float xv[INSZ] = {X0.x, X0.y, X0.z, X0.w, X1.x, X1.y, X1.z, X1.w};
#pragma unroll
    for (int i = 0; i < INSZ; i += 2) {
        const v2f xe = {xv[i], xv[i]};
        const v2f xo = {xv[i + 1], xv[i + 1]};
        a01e = __builtin_elementwise_fma(wx01[i],     xe, a01e);
        a23e = __builtin_elementwise_fma(wx23[i],     xe, a23e);
        a01o = __builtin_elementwise_fma(wx01[i + 1], xo, a01o);
        a23o = __builtin_elementwise_fma(wx23[i + 1], xo, a23o);
    }
#define HTERM(K, A01, A23) do { \
        const float hk = bcast16<K>(hst); \
        const v2f hk2 = {hk, hk}; \
        A01 = __builtin_elementwise_fma(wh01[K], hk2, A01); \
        A23 = __builtin_elementwise_fma(wh23[K], hk2, A23); \
    } while (0)
    HTERM(0, a01e, a23e); HTERM(1, a01o, a23o);
    HTERM(2, a01e, a23e); HTERM(3, a01o, a23o);
    HTERM(4, a01e, a23e); HTERM(5, a01o, a23o);
    HTERM(6, a01e, a23e); HTERM(7, a01o, a23o);
    HTERM(8, a01e, a23e); HTERM(9, a01o, a23o);
#undef HTERM
    const v2f a01 = a01e + a01o;
    const v2f a23 = a23e + a23o;
    // Batched reciprocal: r = 1/(d0 d1 d2 d3); overflow-safe (each d <= ~2^25).
    const float d0 = 1.f + exp2_(a01.x);
    const float d1 = 1.f + exp2_(a01.y);
    const float d2 = 1.f + exp2_(a23.x);
    const float d3 = 1.f + exp2_(a23.y);
    const float p01 = d0 * d1, p23 = d2 * d3;
    const float r   = rcp_(p01 * p23);
    const float r01 = r * p23, r23 = r * p01;
    const float ig = r01 * d1;                    // 1/d0 = sigmoid(i)
    const float fg = r01 * d0;                    // 1/d1 = sigmoid(f)
    const float gg = fmaf(2.f, r23 * d3, -1.f);   // 2/d2-1 = tanh(g)
    const float og = r23 * d2;                    // 1/d3 = sigmoid(o)
    cst = fmaf(fg, cst, ig * gg);
    const float th = fmaf(2.f, rcp_(1.f + exp2_(cst * (-2.f * LOG2E))), -1.f);
    hst = og * th;
}

// One global_load_lds dwordx4: lane l's 16 B -> ldsbase + l*16 (wave-uniform
// base, linear lane layout). Consumers read through LDS (memory), so the
// "memory"-clobbered counted waits order them correctly (R7-proven).
__device__ __forceinline__ void stage_tile(const float* gsrc_lane, float* ldsbase) {
    __builtin_amdgcn_global_load_lds(
        (const __attribute__((address_space(1))) void*)(uintptr_t)gsrc_lane,
        (__attribute__((address_space(3))) void*)(uint32_t)(uintptr_t)ldsbase,
        16, 0, 0);
}

template<int VM>
__device__ __forceinline__ void consume_tile(const float (&xb)[TSTEPS][4][INSZ],
        int grp,
        const v2f (&wx01)[INSZ], const v2f (&wx23)[INSZ],
        const v2f (&wh01)[HID], const v2f (&wh23)[HID],
        const v2f& b01, const v2f& b23, float& hst, float& cst) {
    asm volatile("s_waitcnt vmcnt(%0)" :: "i"(VM) : "memory");
    // Read the whole tile into registers first (one batch of ds_read latency
    // per tile; with waves_per_eu(1,1) the registers are free).
    float4 xlo[TSTEPS], xhi[TSTEPS];
#pragma unroll
    for (int s = 0; s < TSTEPS; ++s) {
        xlo[s] = *(const float4*)&xb[s][grp][0];
        xhi[s] = *(const float4*)&xb[s][grp][4];
    }
#pragma unroll
    for (int s = 0; s < TSTEPS; ++s)
        lstm_step(xlo[s], xhi[s], wx01, wx23, wh01, wh23, b01, b23, hst, cst);
}

// 16 lanes per chain, 4 chains per wave, 1024 waves = 1 wave/SIMD.
// Lane j16<10 owns hidden unit j: gate rows {j,10+j,20+j,30+j}.
// h exchanged via DPP row_newbcast. x staged via 4-deep LDS DMA pipeline.
// waves_per_eu(1,1): max=1 disarms the occupancy-driven register squeeze
// (R14-proven: VGPR 132, weights resident, best wall).
__global__ void __attribute__((amdgpu_flat_work_group_size(64, 64)))
                __attribute__((amdgpu_waves_per_eu(1, 1)))
lstm_fused(
    const float* __restrict__ x,
    const float* __restrict__ h0,
    const float* __restrict__ c0,
    const float* __restrict__ Wih,
    const float* __restrict__ Whh,
    const float* __restrict__ bih,
    const float* __restrict__ bhh,
    const float* __restrict__ Wfc,
    const float* __restrict__ bfc,
    float* __restrict__ out)
{
    __shared__ float xbuf[NBUF][TSTEPS][4][INSZ];   // 4 KB

    const int lane = threadIdx.x;
    const int j16  = lane & 15;
    const int grp  = lane >> 4;
    const int n    = ((int)blockIdx.x << 2) + grp;
    const int j    = (j16 < HID) ? j16 : 0;   // clamp padding lanes
    const int src  = lane & 48;               // 16-lane group base

    const int ri = j, rf = HID + j, rg = 2 * HID + j, ro = 3 * HID + j;
    const float si = -LOG2E, sg = -2.f * LOG2E;

    // Weights as gate-pair float2s (76 regs), activation scale folded in.
    v2f wx01[INSZ], wx23[INSZ], wh01[HID], wh23[HID];
#pragma unroll
    for (int i = 0; i < INSZ; ++i) {
        wx01[i] = (v2f){Wih[ri * INSZ + i] * si, Wih[rf * INSZ + i] * si};
        wx23[i] = (v2f){Wih[rg * INSZ + i] * sg, Wih[ro * INSZ + i] * si};
    }
#pragma unroll
    for (int k = 0; k < HID; ++k) {
        wh01[k] = (v2f){Whh[ri * HID + k] * si, Whh[rf * HID + k] * si};
        wh23[k] = (v2f){Whh[rg * HID + k] * sg, Whh[ro * HID + k] * si};
    }
    const v2f b01 = (v2f){(bih[ri] + bhh[ri]) * si, (bih[rf] + bhh[rf]) * si};
    const v2f b23 = (v2f){(bih[rg] + bhh[rg]) * sg, (bih[ro] + bhh[ro]) * si};

    float cst = c0[n * HID + j];
    float hst = h0[n * HID + j];

    // Per-lane staging source: lane l covers (ts = l>>3, chain = (l>>1)&3,
    // half = l&1) -> LDS byte l*16 matches xbuf[..][ts][chain][half*4..+3].
    const int ts = lane >> 3, ch = (lane >> 1) & 3, hf = lane & 1;
    const float* gl = x + (size_t)ts * XS
                        + (size_t)((((int)blockIdx.x << 2) + ch) * INSZ + hf * 4);

    asm volatile("" ::: "memory");
#pragma unroll
    for (int b = 0; b < NBUF; ++b) {
        stage_tile(gl, &xbuf[b][0][0][0]);
        asm volatile("" ::: "memory");
        gl += (size_t)TSTEPS * XS;
    }

    // Main: counted vmcnt(3) completes exactly the oldest (this tile's) DMA;
    // lgkmcnt(0) ensures the buffer's ds_reads retired before its rewrite.
    for (int tile = 0; tile < NTILES - NBUF; ++tile) {
        const int b = tile & (NBUF - 1);
        consume_tile<3>(xbuf[b], grp, wx01, wx23, wh01, wh23, b01, b23, hst, cst);
        asm volatile("s_waitcnt lgkmcnt(0)" ::: "memory");
        stage_tile(gl, &xbuf[b][0][0][0]);
        asm volatile("" ::: "memory");
        gl += (size_t)TSTEPS * XS;
    }
    // Drain: descending counted waits, no reissue.
    consume_tile<3>(xbuf[0], grp, wx01, wx23, wh01, wh23, b01, b23, hst, cst);
    consume_tile<2>(xbuf[1], grp, wx01, wx23, wh01, wh23, b01, b23, hst, cst);
    consume_tile<1>(xbuf[2], grp, wx01, wx23, wh01, wh23, b01, b23, hst, cst);
    consume_tile<0>(xbuf[3], grp, wx01, wx23, wh01, wh23, b01, b23, hst, cst);

    // epilogue (one-time, DS shuffles fine here): y = h @ W_fc.T + b_fc; dump h, c
    float hv[HID];
#pragma unroll
    for (int k = 0; k < HID; ++k) hv[k] = __shfl(hst, src + k, 64);

    if (j16 < INSZ) {
        float acc = bfc[j16];
#pragma unroll
        for (int k = 0; k < HID; ++k) acc = fmaf(Wfc[j16 * HID + k], hv[k], acc);
        out[n * INSZ + j16] = acc;
    }
    if (j16 < HID) {
        out[NB * INSZ + n * HID + j16] = hst;
        out[NB * INSZ + NB * HID + n * HID + j16] = cst;
    }
}

extern "C" void kernel_launch(void* const* d_in, const int* in_sizes, int n_in,
                              void* d_out, int out_size, void* d_ws, size_t ws_size,
                              hipStream_t stream) {
    const float* x   = (const float*)d_in[0];
    const float* h0  = (const float*)d_in[1];
    const float* c0  = (const float*)d_in[2];
    const float* Wih = (const float*)d_in[3];
    const float* Whh = (const float*)d_in[4];
    const float* bih = (const float*)d_in[5];
    const float* bhh = (const float*)d_in[6];
    const float* Wfc = (const float*)d_in[7];
    const float* bfc = (const float*)d_in[8];
    float* out = (float*)d_out;

    lstm_fused<<<NB / 4, 64, 0, stream>>>(x, h0, c0, Wih, Whh, bih, bhh, Wfc, bfc, out);
}